// Round 1
// baseline (211.433 us; speedup 1.0000x reference)
//
#include <hip/hip_runtime.h>
#include <hip/hip_bf16.h>

#define DEV __device__ __forceinline__

typedef __attribute__((ext_vector_type(8))) short bf16x8;
typedef __attribute__((ext_vector_type(4))) float f32x4;

static constexpr int NR   = 16384;
static constexpr int DIN  = 512;
static constexpr int DHID = 2048;
static constexpr int DOUT = 512;
static constexpr int LR   = 64;          // 4 bands * rank 16
static constexpr int K1   = DIN + LR;    // 576
static constexpr int K2   = DHID + LR;   // 2112

DEV unsigned short f2bf(float f) {
  unsigned u = __float_as_uint(f);
  u += 0x7fffu + ((u >> 16) & 1u);
  return (unsigned short)(u >> 16);
}

// ---- x fp32 -> bf16 into xaug[:, 0:512] (row stride K1) ----
__global__ __launch_bounds__(256) void cvt_x_kernel(const float* __restrict__ x,
                                                    unsigned short* __restrict__ xaug) {
  int i = blockIdx.x * 256 + threadIdx.x;   // one float4 per thread
  if (i >= NR * DIN / 4) return;
  int e = i * 4;
  int r = e >> 9, c = e & 511;
  float4 v = ((const float4*)x)[i];
  uint2 o;
  o.x = (unsigned)f2bf(v.x) | ((unsigned)f2bf(v.y) << 16);
  o.y = (unsigned)f2bf(v.z) | ((unsigned)f2bf(v.w) << 16);
  *(uint2*)(xaug + (size_t)r * K1 + c) = o;
}

// ---- generic transpose+convert: in fp32 [R][C] -> out bf16 [C][LDO] at col offset CO ----
template<int R, int C, int LDO, int CO>
__global__ __launch_bounds__(256) void tconv_kernel(const float* __restrict__ in,
                                                    unsigned short* __restrict__ out) {
  __shared__ float t[32][33];
  int bc = blockIdx.x * 32, br = blockIdx.y * 32;
  int tx = threadIdx.x & 31, ty = threadIdx.x >> 5;   // ty 0..7
  #pragma unroll
  for (int i = 0; i < 32; i += 8)
    t[ty + i][tx] = in[(size_t)(br + ty + i) * C + bc + tx];
  __syncthreads();
  #pragma unroll
  for (int i = 0; i < 32; i += 8)
    out[(size_t)(bc + ty + i) * LDO + CO + br + tx] = f2bf(t[tx][ty + i]);
}

// ---- LoRA A rearrange: A [4][D][16] fp32 -> AT [64][D] bf16 ----
__global__ __launch_bounds__(256) void rearrA_kernel(const float* __restrict__ A,
                                                     unsigned short* __restrict__ AT, int D) {
  int tid = blockIdx.x * 256 + threadIdx.x;
  if (tid >= 64 * D) return;
  int j = tid / D, i = tid - j * D;
  AT[tid] = f2bf(A[((size_t)(j >> 4) * D + i) * 16 + (j & 15)]);
}

// ---- main MFMA GEMM, m97-style 2-phase, BK=64 ----
// A: [M][lda] bf16 K-contig rows. B: [Ncols][ldb] bf16 K-contig rows (i.e. weight^T).
// EPI: 0 = gelu(acc+bias) -> bf16 out ; 1 = acc+bias -> fp32 out ; 2 = acc*2*bw[row][col>>4] -> bf16 out
template<int BM, int BN, int WM, int WN, int K, int EPI>
__global__ __launch_bounds__(256) void gemm_kernel(
    const unsigned short* __restrict__ A, int lda,
    const unsigned short* __restrict__ B, int ldb,
    const float* __restrict__ bias, const float* __restrict__ bw,
    void* __restrict__ outp, int ldo, int ocol) {
  constexpr int WRM = WM / 16, WRN = WN / 16;
  constexpr int NWN = BN / WN;
  static_assert((BM / WM) * (BN / WN) == 4, "4 waves");
  constexpr int AISS = BM * 64 * 2 / 4096;
  constexpr int BISS = BN * 64 * 2 / 4096;
  __shared__ __align__(16) unsigned short lA[BM * 64];
  __shared__ __align__(16) unsigned short lB[BN * 64];

  const int tid  = threadIdx.x;
  const int wid  = tid >> 6, lane = tid & 63;
  const int wr   = wid / NWN, wc = wid % NWN;
  const int bm   = blockIdx.x * BM, bn = blockIdx.y * BN;
  const int srow = lane >> 3;          // row within 8-row group
  const int scol = (lane & 7) * 8;     // 8-elem (16B) column chunk

  f32x4 acc[WRM][WRN] = {};

  for (int k0 = 0; k0 < K; k0 += 64) {
    #pragma unroll
    for (int i = 0; i < AISS; i++) {
      int rowbase = i * 32 + wid * 8;
      __builtin_amdgcn_global_load_lds(
          (const __attribute__((address_space(1))) void*)
              (A + (size_t)(bm + rowbase + srow) * lda + k0 + scol),
          (__attribute__((address_space(3))) void*)(lA + i * 2048 + wid * 512),
          16, 0, 0);
    }
    #pragma unroll
    for (int i = 0; i < BISS; i++) {
      int rowbase = i * 32 + wid * 8;
      __builtin_amdgcn_global_load_lds(
          (const __attribute__((address_space(1))) void*)
              (B + (size_t)(bn + rowbase + srow) * ldb + k0 + scol),
          (__attribute__((address_space(3))) void*)(lB + i * 2048 + wid * 512),
          16, 0, 0);
    }
    __syncthreads();
    #pragma unroll
    for (int ks = 0; ks < 2; ks++) {
      bf16x8 af[WRM], bfv[WRN];
      #pragma unroll
      for (int m = 0; m < WRM; m++)
        af[m] = *(const bf16x8*)(lA + (wr * WM + m * 16 + (lane & 15)) * 64 + ks * 32 + (lane >> 4) * 8);
      #pragma unroll
      for (int n = 0; n < WRN; n++)
        bfv[n] = *(const bf16x8*)(lB + (wc * WN + n * 16 + (lane & 15)) * 64 + ks * 32 + (lane >> 4) * 8);
      #pragma unroll
      for (int m = 0; m < WRM; m++)
        #pragma unroll
        for (int n = 0; n < WRN; n++)
          acc[m][n] = __builtin_amdgcn_mfma_f32_16x16x32_bf16(af[m], bfv[n], acc[m][n], 0, 0, 0);
    }
    __syncthreads();
  }

  // epilogue: C/D layout col=lane&15, row=(lane>>4)*4+reg (verified m89/m91)
  const int r0 = bm + wr * WM;
  const int c0 = bn + wc * WN;
  #pragma unroll
  for (int m = 0; m < WRM; m++) {
    #pragma unroll
    for (int n = 0; n < WRN; n++) {
      int col  = c0 + n * 16 + (lane & 15);
      int rowb = r0 + m * 16 + ((lane >> 4) << 2);
      #pragma unroll
      for (int r = 0; r < 4; r++) {
        float v = acc[m][n][r];
        int row = rowb + r;
        if (EPI == 0) {
          v += bias[col];
          v = 0.5f * v * (1.0f + erff(v * 0.70710678118654752f));
          ((unsigned short*)outp)[(size_t)row * ldo + ocol + col] = f2bf(v);
        } else if (EPI == 1) {
          v += bias[col];
          ((float*)outp)[(size_t)row * ldo + col] = v;
        } else {
          v *= 2.0f * bw[row * 4 + (col >> 4)];
          ((unsigned short*)outp)[(size_t)row * ldo + ocol + col] = f2bf(v);
        }
      }
    }
  }
}

extern "C" void kernel_launch(void* const* d_in, const int* in_sizes, int n_in,
                              void* d_out, int out_size, void* d_ws, size_t ws_size,
                              hipStream_t stream) {
  const float* x  = (const float*)d_in[0];
  const float* bw = (const float*)d_in[1];
  const float* W1 = (const float*)d_in[2];
  const float* b1 = (const float*)d_in[3];
  const float* W2 = (const float*)d_in[4];
  const float* b2 = (const float*)d_in[5];
  const float* A1 = (const float*)d_in[6];
  const float* B1 = (const float*)d_in[7];
  const float* A2 = (const float*)d_in[8];
  const float* B2 = (const float*)d_in[9];
  float* out = (float*)d_out;

  char* w = (char*)d_ws;
  unsigned short* xaug = (unsigned short*)w;  w += (size_t)NR * K1 * 2;       // 18.9 MB
  unsigned short* haug = (unsigned short*)w;  w += (size_t)NR * K2 * 2;       // 69.2 MB
  unsigned short* W1cT = (unsigned short*)w;  w += (size_t)DHID * K1 * 2;     // 2.36 MB
  unsigned short* W2cT = (unsigned short*)w;  w += (size_t)DOUT * K2 * 2;     // 2.16 MB
  unsigned short* A1T  = (unsigned short*)w;  w += (size_t)64 * DIN * 2;
  unsigned short* A2T  = (unsigned short*)w;  w += (size_t)64 * DHID * 2;

  // --- preprocessing ---
  cvt_x_kernel<<<NR * DIN / 4 / 256, 256, 0, stream>>>(x, xaug);
  tconv_kernel<512, 2048, K1, 0><<<dim3(64, 16), 256, 0, stream>>>(W1, W1cT);
  tconv_kernel<64, 2048, K1, 512><<<dim3(64, 2), 256, 0, stream>>>(B1, W1cT);
  tconv_kernel<2048, 512, K2, 0><<<dim3(16, 64), 256, 0, stream>>>(W2, W2cT);
  tconv_kernel<64, 512, K2, 2048><<<dim3(16, 2), 256, 0, stream>>>(B2, W2cT);
  rearrA_kernel<<<128, 256, 0, stream>>>(A1, A1T, 512);
  rearrA_kernel<<<512, 256, 0, stream>>>(A2, A2T, 2048);

  // --- u1 = 2*bw ⊙ (x @ A1cat)  -> xaug[:, 512:576] ---
  gemm_kernel<64, 64, 32, 32, 512, 2><<<dim3(NR / 64, 1), 256, 0, stream>>>(
      xaug, K1, A1T, DIN, nullptr, bw, xaug, K1, 512);
  // --- h = gelu(xaug @ [W1;B1cat] + b1) -> haug[:, 0:2048] ---
  gemm_kernel<128, 128, 64, 64, K1, 0><<<dim3(NR / 128, DHID / 128), 256, 0, stream>>>(
      xaug, K1, W1cT, K1, b1, nullptr, haug, K2, 0);
  // --- u2 = 2*bw ⊙ (h @ A2cat) -> haug[:, 2048:2112] ---
  gemm_kernel<64, 64, 32, 32, 2048, 2><<<dim3(NR / 64, 1), 256, 0, stream>>>(
      haug, K2, A2T, DHID, nullptr, bw, haug, K2, 2048);
  // --- out = haug @ [W2;B2cat] + b2 (fp32) ---
  gemm_kernel<128, 128, 64, 64, K2, 1><<<dim3(NR / 128, DOUT / 128), 256, 0, stream>>>(
      haug, K2, W2cT, K2, b2, nullptr, out, DOUT, 0);
}

// Round 2
// 187.012 us; speedup vs baseline: 1.1306x; 1.1306x over previous
//
#include <hip/hip_runtime.h>
#include <hip/hip_bf16.h>

#define DEV __device__ __forceinline__

typedef __attribute__((ext_vector_type(8))) short bf16x8;
typedef __attribute__((ext_vector_type(4))) float f32x4;

static constexpr int NR   = 16384;
static constexpr int DIN  = 512;
static constexpr int DHID = 2048;
static constexpr int DOUT = 512;
static constexpr int LR   = 64;          // 4 bands * rank 16
static constexpr int K1   = DIN + LR;    // 576
static constexpr int K2   = DHID + LR;   // 2112

DEV unsigned short f2bf(float f) {
  unsigned u = __float_as_uint(f);
  u += 0x7fffu + ((u >> 16) & 1u);
  return (unsigned short)(u >> 16);
}

// fast GELU: tanh-form, |err vs erf-form| < ~1.5e-3 (well under bf16 quantum of h)
// gelu(x) = x / (1 + exp2(-(c1*x + c3*x^3))), c = 2*0.7978845608*log2(e)
DEV float fast_gelu(float v) {
  float x2 = v * v;
  float a  = -v * __builtin_fmaf(0.10294324f, x2, 2.30220817f);
  float t  = exp2f(a);
  return v * __builtin_amdgcn_rcpf(1.0f + t);
}

// ---- x fp32 -> bf16 into xaug[:, 0:512] (row stride K1) ----
__global__ __launch_bounds__(256) void cvt_x_kernel(const float* __restrict__ x,
                                                    unsigned short* __restrict__ xaug) {
  int i = blockIdx.x * 256 + threadIdx.x;   // one float4 per thread
  if (i >= NR * DIN / 4) return;
  int e = i * 4;
  int r = e >> 9, c = e & 511;
  float4 v = ((const float4*)x)[i];
  uint2 o;
  o.x = (unsigned)f2bf(v.x) | ((unsigned)f2bf(v.y) << 16);
  o.y = (unsigned)f2bf(v.z) | ((unsigned)f2bf(v.w) << 16);
  *(uint2*)(xaug + (size_t)r * K1 + c) = o;
}

// ---- generic transpose+convert: in fp32 [R][C] -> out bf16 [C][LDO] at col offset CO ----
template<int R, int C, int LDO, int CO>
__global__ __launch_bounds__(256) void tconv_kernel(const float* __restrict__ in,
                                                    unsigned short* __restrict__ out) {
  __shared__ float t[32][33];
  int bc = blockIdx.x * 32, br = blockIdx.y * 32;
  int tx = threadIdx.x & 31, ty = threadIdx.x >> 5;   // ty 0..7
  #pragma unroll
  for (int i = 0; i < 32; i += 8)
    t[ty + i][tx] = in[(size_t)(br + ty + i) * C + bc + tx];
  __syncthreads();
  #pragma unroll
  for (int i = 0; i < 32; i += 8)
    out[(size_t)(bc + ty + i) * LDO + CO + br + tx] = f2bf(t[tx][ty + i]);
}

// ---- LoRA A rearrange: A [4][D][16] fp32 -> AT [64][D] bf16 ----
__global__ __launch_bounds__(256) void rearrA_kernel(const float* __restrict__ A,
                                                     unsigned short* __restrict__ AT, int D) {
  int tid = blockIdx.x * 256 + threadIdx.x;
  if (tid >= 64 * D) return;
  int j = tid / D, i = tid - j * D;
  AT[tid] = f2bf(A[((size_t)(j >> 4) * D + i) * 16 + (j & 15)]);
}

// ---- main MFMA GEMM, m97-style 2-phase, BK=64 ----
// A: [M][lda] bf16 K-contig rows. B: [Ncols][ldb] bf16 K-contig rows (i.e. weight^T).
// EPI: 0 = gelu(acc+bias) -> bf16 out ; 1 = acc+bias -> fp32 out ; 2 = acc*2*bw[row][col>>4] -> bf16 out
template<int BM, int BN, int WM, int WN, int K, int EPI>
__global__ __launch_bounds__(256) void gemm_kernel(
    const unsigned short* __restrict__ A, int lda,
    const unsigned short* __restrict__ B, int ldb,
    const float* __restrict__ bias, const float* __restrict__ bw,
    void* __restrict__ outp, int ldo, int ocol) {
  constexpr int WRM = WM / 16, WRN = WN / 16;
  constexpr int NWN = BN / WN;
  static_assert((BM / WM) * (BN / WN) == 4, "4 waves");
  constexpr int AISS = BM * 64 * 2 / 4096;
  constexpr int BISS = BN * 64 * 2 / 4096;
  __shared__ __align__(16) unsigned short lA[BM * 64];
  __shared__ __align__(16) unsigned short lB[BN * 64];

  const int tid  = threadIdx.x;
  const int wid  = tid >> 6, lane = tid & 63;
  const int wr   = wid / NWN, wc = wid % NWN;
  const int bm   = blockIdx.x * BM, bn = blockIdx.y * BN;
  const int srow = lane >> 3;          // row within 8-row group
  const int scol = (lane & 7) * 8;     // 8-elem (16B) column chunk

  f32x4 acc[WRM][WRN] = {};

  for (int k0 = 0; k0 < K; k0 += 64) {
    #pragma unroll
    for (int i = 0; i < AISS; i++) {
      int rowbase = i * 32 + wid * 8;
      __builtin_amdgcn_global_load_lds(
          (const __attribute__((address_space(1))) void*)
              (A + (size_t)(bm + rowbase + srow) * lda + k0 + scol),
          (__attribute__((address_space(3))) void*)(lA + i * 2048 + wid * 512),
          16, 0, 0);
    }
    #pragma unroll
    for (int i = 0; i < BISS; i++) {
      int rowbase = i * 32 + wid * 8;
      __builtin_amdgcn_global_load_lds(
          (const __attribute__((address_space(1))) void*)
              (B + (size_t)(bn + rowbase + srow) * ldb + k0 + scol),
          (__attribute__((address_space(3))) void*)(lB + i * 2048 + wid * 512),
          16, 0, 0);
    }
    __syncthreads();
    #pragma unroll
    for (int ks = 0; ks < 2; ks++) {
      bf16x8 af[WRM], bfv[WRN];
      #pragma unroll
      for (int m = 0; m < WRM; m++)
        af[m] = *(const bf16x8*)(lA + (wr * WM + m * 16 + (lane & 15)) * 64 + ks * 32 + (lane >> 4) * 8);
      #pragma unroll
      for (int n = 0; n < WRN; n++)
        bfv[n] = *(const bf16x8*)(lB + (wc * WN + n * 16 + (lane & 15)) * 64 + ks * 32 + (lane >> 4) * 8);
      #pragma unroll
      for (int m = 0; m < WRM; m++)
        #pragma unroll
        for (int n = 0; n < WRN; n++)
          acc[m][n] = __builtin_amdgcn_mfma_f32_16x16x32_bf16(af[m], bfv[n], acc[m][n], 0, 0, 0);
    }
    __syncthreads();
  }

  // epilogue: C/D layout col=lane&15, row=(lane>>4)*4+reg (verified m89/m91)
  const int r0 = bm + wr * WM;
  const int c0 = bn + wc * WN;

  // hoist bias per output column (col depends on n only)
  float biasv[WRN];
  if (EPI != 2) {
    #pragma unroll
    for (int n = 0; n < WRN; n++)
      biasv[n] = bias[c0 + n * 16 + (lane & 15)];
  }

  #pragma unroll
  for (int m = 0; m < WRM; m++) {
    #pragma unroll
    for (int n = 0; n < WRN; n++) {
      int col  = c0 + n * 16 + (lane & 15);
      int rowb = r0 + m * 16 + ((lane >> 4) << 2);
      #pragma unroll
      for (int r = 0; r < 4; r++) {
        float v = acc[m][n][r];
        int row = rowb + r;
        if (EPI == 0) {
          v = fast_gelu(v + biasv[n]);
          ((unsigned short*)outp)[(size_t)row * ldo + ocol + col] = f2bf(v);
        } else if (EPI == 1) {
          v += biasv[n];
          ((float*)outp)[(size_t)row * ldo + col] = v;
        } else {
          v *= 2.0f * bw[row * 4 + (col >> 4)];
          ((unsigned short*)outp)[(size_t)row * ldo + ocol + col] = f2bf(v);
        }
      }
    }
  }
}

extern "C" void kernel_launch(void* const* d_in, const int* in_sizes, int n_in,
                              void* d_out, int out_size, void* d_ws, size_t ws_size,
                              hipStream_t stream) {
  const float* x  = (const float*)d_in[0];
  const float* bw = (const float*)d_in[1];
  const float* W1 = (const float*)d_in[2];
  const float* b1 = (const float*)d_in[3];
  const float* W2 = (const float*)d_in[4];
  const float* b2 = (const float*)d_in[5];
  const float* A1 = (const float*)d_in[6];
  const float* B1 = (const float*)d_in[7];
  const float* A2 = (const float*)d_in[8];
  const float* B2 = (const float*)d_in[9];
  float* out = (float*)d_out;

  char* w = (char*)d_ws;
  unsigned short* xaug = (unsigned short*)w;  w += (size_t)NR * K1 * 2;       // 18.9 MB
  unsigned short* haug = (unsigned short*)w;  w += (size_t)NR * K2 * 2;       // 69.2 MB
  unsigned short* W1cT = (unsigned short*)w;  w += (size_t)DHID * K1 * 2;     // 2.36 MB
  unsigned short* W2cT = (unsigned short*)w;  w += (size_t)DOUT * K2 * 2;     // 2.16 MB
  unsigned short* A1T  = (unsigned short*)w;  w += (size_t)64 * DIN * 2;
  unsigned short* A2T  = (unsigned short*)w;  w += (size_t)64 * DHID * 2;

  // --- preprocessing ---
  cvt_x_kernel<<<NR * DIN / 4 / 256, 256, 0, stream>>>(x, xaug);
  tconv_kernel<512, 2048, K1, 0><<<dim3(64, 16), 256, 0, stream>>>(W1, W1cT);
  tconv_kernel<64, 2048, K1, 512><<<dim3(64, 2), 256, 0, stream>>>(B1, W1cT);
  tconv_kernel<2048, 512, K2, 0><<<dim3(16, 64), 256, 0, stream>>>(W2, W2cT);
  tconv_kernel<64, 512, K2, 2048><<<dim3(16, 2), 256, 0, stream>>>(B2, W2cT);
  rearrA_kernel<<<128, 256, 0, stream>>>(A1, A1T, 512);
  rearrA_kernel<<<512, 256, 0, stream>>>(A2, A2T, 2048);

  // --- u1 = 2*bw ⊙ (x @ A1cat)  -> xaug[:, 512:576] ---
  gemm_kernel<64, 64, 32, 32, 512, 2><<<dim3(NR / 64, 1), 256, 0, stream>>>(
      xaug, K1, A1T, DIN, nullptr, bw, xaug, K1, 512);
  // --- h = gelu(xaug @ [W1;B1cat] + b1) -> haug[:, 0:2048] ---
  gemm_kernel<128, 128, 64, 64, K1, 0><<<dim3(NR / 128, DHID / 128), 256, 0, stream>>>(
      xaug, K1, W1cT, K1, b1, nullptr, haug, K2, 0);
  // --- u2 = 2*bw ⊙ (h @ A2cat) -> haug[:, 2048:2112] ---
  gemm_kernel<64, 64, 32, 32, 2048, 2><<<dim3(NR / 64, 1), 256, 0, stream>>>(
      haug, K2, A2T, DHID, nullptr, bw, haug, K2, 2048);
  // --- out = haug @ [W2;B2cat] + b2 (fp32) ---
  gemm_kernel<128, 128, 64, 64, K2, 1><<<dim3(NR / 128, DOUT / 128), 256, 0, stream>>>(
      haug, K2, W2cT, K2, b2, nullptr, out, DOUT, 0);
}

// Round 3
// 170.160 us; speedup vs baseline: 1.2426x; 1.0990x over previous
//
#include <hip/hip_runtime.h>
#include <hip/hip_bf16.h>

#define DEV __device__ __forceinline__

typedef __attribute__((ext_vector_type(8))) short bf16x8;
typedef __attribute__((ext_vector_type(4))) float f32x4;

static constexpr int NR   = 16384;
static constexpr int DIN  = 512;
static constexpr int DHID = 2048;
static constexpr int DOUT = 512;
static constexpr int LR   = 64;          // 4 bands * rank 16
static constexpr int K1   = DIN + LR;    // 576
static constexpr int K2   = DHID + LR;   // 2112

DEV unsigned short f2bf(float f) {
  unsigned u = __float_as_uint(f);
  u += 0x7fffu + ((u >> 16) & 1u);
  return (unsigned short)(u >> 16);
}

// fast GELU: tanh-form, |err vs erf-form| < ~1.5e-3 (well under bf16 quantum of h)
DEV float fast_gelu(float v) {
  float x2 = v * v;
  float a  = -v * __builtin_fmaf(0.10294324f, x2, 2.30220817f);
  float t  = exp2f(a);
  return v * __builtin_amdgcn_rcpf(1.0f + t);
}

// ---- x fp32 -> bf16 into xaug[:, 0:512] (row stride K1) ----
__global__ __launch_bounds__(256) void cvt_x_kernel(const float* __restrict__ x,
                                                    unsigned short* __restrict__ xaug) {
  int i = blockIdx.x * 256 + threadIdx.x;   // one float4 per thread
  if (i >= NR * DIN / 4) return;
  int e = i * 4;
  int r = e >> 9, c = e & 511;
  float4 v = ((const float4*)x)[i];
  uint2 o;
  o.x = (unsigned)f2bf(v.x) | ((unsigned)f2bf(v.y) << 16);
  o.y = (unsigned)f2bf(v.z) | ((unsigned)f2bf(v.w) << 16);
  *(uint2*)(xaug + (size_t)r * K1 + c) = o;
}

// ---- generic transpose+convert: in fp32 [R][C] -> out bf16 [C][LDO] at col offset CO ----
template<int R, int C, int LDO, int CO>
__global__ __launch_bounds__(256) void tconv_kernel(const float* __restrict__ in,
                                                    unsigned short* __restrict__ out) {
  __shared__ float t[32][33];
  int bc = blockIdx.x * 32, br = blockIdx.y * 32;
  int tx = threadIdx.x & 31, ty = threadIdx.x >> 5;   // ty 0..7
  #pragma unroll
  for (int i = 0; i < 32; i += 8)
    t[ty + i][tx] = in[(size_t)(br + ty + i) * C + bc + tx];
  __syncthreads();
  #pragma unroll
  for (int i = 0; i < 32; i += 8)
    out[(size_t)(bc + ty + i) * LDO + CO + br + tx] = f2bf(t[tx][ty + i]);
}

// ---- LoRA A rearrange: A [4][D][16] fp32 -> AT [64][D] bf16 ----
__global__ __launch_bounds__(256) void rearrA_kernel(const float* __restrict__ A,
                                                     unsigned short* __restrict__ AT, int D) {
  int tid = blockIdx.x * 256 + threadIdx.x;
  if (tid >= 64 * D) return;
  int j = tid / D, i = tid - j * D;
  AT[tid] = f2bf(A[((size_t)(j >> 4) * D + i) * 16 + (j & 15)]);
}

// ---- main MFMA GEMM: prefetch double-buffered (T3-minimum), BK=32,
//      source-swizzled LDS (T2 via m173: swizzle global src chunk, linear LDS dst,
//      matching XOR on ds_read).
// A: [M][lda] bf16 K-contig rows. B: [Ncols][ldb] bf16 K-contig rows (weight^T).
// EPI: 0 = gelu(acc+bias)->bf16 ; 1 = acc+bias->fp32 ; 2 = acc*2*bw[row][col>>4]->bf16
template<int BM, int BN, int WM, int WN, int K, int EPI>
__global__ __launch_bounds__(256) void gemm_kernel(
    const unsigned short* __restrict__ A, int lda,
    const unsigned short* __restrict__ B, int ldb,
    const float* __restrict__ bias, const float* __restrict__ bw,
    void* __restrict__ outp, int ldo, int ocol) {
  constexpr int WRM = WM / 16, WRN = WN / 16;
  constexpr int NWN = BN / WN;
  constexpr int NT  = K / 32;
  static_assert((BM / WM) * (BN / WN) == 4, "4 waves");
  static_assert(NT % 2 == 0, "even tile count");
  constexpr int AISS = BM / 64;   // global_load_lds per thread for A per K-tile
  constexpr int BISS = BN / 64;
  __shared__ __align__(16) unsigned short lA[2 * BM * 32];
  __shared__ __align__(16) unsigned short lB[2 * BN * 32];

  const int tid  = threadIdx.x;
  const int wid  = tid >> 6, lane = tid & 63;
  const int wr   = wid / NWN, wc = wid % NWN;
  const int bm   = blockIdx.x * BM, bn = blockIdx.y * BN;
  // staging: 64 lanes = 16 rows x 4 chunks (16B each); src chunk XOR-swizzled by row&3
  const int srow = lane >> 2;
  const int scol = (((lane & 3) ^ ((lane >> 2) & 3)) * 8);
  // ds_read fragment chunk: logical (lane>>4) XOR row&3 (= lane&3 since row = ...16m + (lane&15))
  const int kch  = (((lane >> 4) ^ (lane & 3)) * 8);

  f32x4 acc[WRM][WRN] = {};

  auto stage = [&](int buf, int t) {
    #pragma unroll
    for (int i = 0; i < AISS; i++) {
      int row = i * 64 + wid * 16 + srow;
      __builtin_amdgcn_global_load_lds(
          (const __attribute__((address_space(1))) void*)
              (A + (size_t)(bm + row) * lda + t * 32 + scol),
          (__attribute__((address_space(3))) void*)(lA + buf * (BM * 32) + i * 2048 + wid * 512),
          16, 0, 0);
    }
    #pragma unroll
    for (int i = 0; i < BISS; i++) {
      int row = i * 64 + wid * 16 + srow;
      __builtin_amdgcn_global_load_lds(
          (const __attribute__((address_space(1))) void*)
              (B + (size_t)(bn + row) * ldb + t * 32 + scol),
          (__attribute__((address_space(3))) void*)(lB + buf * (BN * 32) + i * 2048 + wid * 512),
          16, 0, 0);
    }
  };

  auto compute = [&](int buf) {
    const unsigned short* pA = lA + buf * (BM * 32);
    const unsigned short* pB = lB + buf * (BN * 32);
    bf16x8 af[WRM], bfv[WRN];
    #pragma unroll
    for (int m = 0; m < WRM; m++)
      af[m] = *(const bf16x8*)(pA + (wr * WM + m * 16 + (lane & 15)) * 32 + kch);
    #pragma unroll
    for (int n = 0; n < WRN; n++)
      bfv[n] = *(const bf16x8*)(pB + (wc * WN + n * 16 + (lane & 15)) * 32 + kch);
    #pragma unroll
    for (int m = 0; m < WRM; m++)
      #pragma unroll
      for (int n = 0; n < WRN; n++)
        acc[m][n] = __builtin_amdgcn_mfma_f32_16x16x32_bf16(af[m], bfv[n], acc[m][n], 0, 0, 0);
  };

  // prologue
  stage(0, 0);
  __syncthreads();                       // implicit vmcnt(0) drain -> buf0 ready
  // main loop: 2 tiles/iter so buffer index is compile-time static
  for (int t = 0; t < NT; t += 2) {
    if (t + 1 < NT) stage(1, t + 1);     // prefetch overlaps compute(0)
    compute(0);
    __syncthreads();                     // drains vmcnt -> buf1 ready; buf0 reads done
    if (t + 2 < NT) stage(0, t + 2);
    compute(1);
    __syncthreads();
  }

  // epilogue: C/D layout col=lane&15, row=(lane>>4)*4+reg (verified m89/m91)
  const int r0 = bm + wr * WM;
  const int c0 = bn + wc * WN;

  float biasv[WRN];
  if (EPI != 2) {
    #pragma unroll
    for (int n = 0; n < WRN; n++)
      biasv[n] = bias[c0 + n * 16 + (lane & 15)];
  }

  #pragma unroll
  for (int m = 0; m < WRM; m++) {
    #pragma unroll
    for (int n = 0; n < WRN; n++) {
      int col  = c0 + n * 16 + (lane & 15);
      int rowb = r0 + m * 16 + ((lane >> 4) << 2);
      #pragma unroll
      for (int r = 0; r < 4; r++) {
        float v = acc[m][n][r];
        int row = rowb + r;
        if (EPI == 0) {
          v = fast_gelu(v + biasv[n]);
          ((unsigned short*)outp)[(size_t)row * ldo + ocol + col] = f2bf(v);
        } else if (EPI == 1) {
          v += biasv[n];
          ((float*)outp)[(size_t)row * ldo + col] = v;
        } else {
          v *= 2.0f * bw[row * 4 + (col >> 4)];
          ((unsigned short*)outp)[(size_t)row * ldo + ocol + col] = f2bf(v);
        }
      }
    }
  }
}

extern "C" void kernel_launch(void* const* d_in, const int* in_sizes, int n_in,
                              void* d_out, int out_size, void* d_ws, size_t ws_size,
                              hipStream_t stream) {
  const float* x  = (const float*)d_in[0];
  const float* bw = (const float*)d_in[1];
  const float* W1 = (const float*)d_in[2];
  const float* b1 = (const float*)d_in[3];
  const float* W2 = (const float*)d_in[4];
  const float* b2 = (const float*)d_in[5];
  const float* A1 = (const float*)d_in[6];
  const float* B1 = (const float*)d_in[7];
  const float* A2 = (const float*)d_in[8];
  const float* B2 = (const float*)d_in[9];
  float* out = (float*)d_out;

  char* w = (char*)d_ws;
  unsigned short* xaug = (unsigned short*)w;  w += (size_t)NR * K1 * 2;       // 18.9 MB
  unsigned short* haug = (unsigned short*)w;  w += (size_t)NR * K2 * 2;       // 69.2 MB
  unsigned short* W1cT = (unsigned short*)w;  w += (size_t)DHID * K1 * 2;     // 2.36 MB
  unsigned short* W2cT = (unsigned short*)w;  w += (size_t)DOUT * K2 * 2;     // 2.16 MB
  unsigned short* A1T  = (unsigned short*)w;  w += (size_t)64 * DIN * 2;
  unsigned short* A2T  = (unsigned short*)w;  w += (size_t)64 * DHID * 2;

  // --- preprocessing ---
  cvt_x_kernel<<<NR * DIN / 4 / 256, 256, 0, stream>>>(x, xaug);
  tconv_kernel<512, 2048, K1, 0><<<dim3(64, 16), 256, 0, stream>>>(W1, W1cT);
  tconv_kernel<64, 2048, K1, 512><<<dim3(64, 2), 256, 0, stream>>>(B1, W1cT);
  tconv_kernel<2048, 512, K2, 0><<<dim3(16, 64), 256, 0, stream>>>(W2, W2cT);
  tconv_kernel<64, 512, K2, 2048><<<dim3(16, 2), 256, 0, stream>>>(B2, W2cT);
  rearrA_kernel<<<128, 256, 0, stream>>>(A1, A1T, 512);
  rearrA_kernel<<<512, 256, 0, stream>>>(A2, A2T, 2048);

  // --- u1 = 2*bw ⊙ (x @ A1cat)  -> xaug[:, 512:576] ---
  gemm_kernel<64, 64, 32, 32, 512, 2><<<dim3(NR / 64, 1), 256, 0, stream>>>(
      xaug, K1, A1T, DIN, nullptr, bw, xaug, K1, 512);
  // --- h = gelu(xaug @ [W1;B1cat] + b1) -> haug[:, 0:2048] ---
  gemm_kernel<128, 128, 64, 64, K1, 0><<<dim3(NR / 128, DHID / 128), 256, 0, stream>>>(
      xaug, K1, W1cT, K1, b1, nullptr, haug, K2, 0);
  // --- u2 = 2*bw ⊙ (h @ A2cat) -> haug[:, 2048:2112] ---
  gemm_kernel<64, 64, 32, 32, 2048, 2><<<dim3(NR / 64, 1), 256, 0, stream>>>(
      haug, K2, A2T, DHID, nullptr, bw, haug, K2, 2048);
  // --- out = haug @ [W2;B2cat] + b2 (fp32) ---
  gemm_kernel<128, 128, 64, 64, K2, 1><<<dim3(NR / 128, DOUT / 128), 256, 0, stream>>>(
      haug, K2, W2cT, K2, b2, nullptr, out, DOUT, 0);
}